// Round 5
// baseline (464.898 us; speedup 1.0000x reference)
//
#include <hip/hip_runtime.h>
#include <math.h>

#define T_LEN 100
#define K_LEN 25
#define DLAT 64
#define DHID 128

// ---------------------------------------------------------------------------
// buildWc: fold Conv1d+fc1+{rel,root} projections into one 256x100 matrix:
//   U[n,j] = sum_i x[n,i]*Wc[j,i] + bc[j]
//   j <  128: P[n,j] (rel path, pre-aggregation)   Wc[j,:] = rel_w[j,:] @ W
//   j >= 128: R[n,j'] (root path + rel_b)          Wc[j,:] = root_w[j',:] @ W
//   W[c,i] = sum_t fc1_w[t] * conv_w[c, i-t+12]
// ---------------------------------------------------------------------------
__global__ __launch_bounds__(256) void buildWc(const float* __restrict__ conv_w,
                                               const float* __restrict__ conv_b,
                                               const float* __restrict__ fc1_w,
                                               const float* __restrict__ fc1_b,
                                               const float* __restrict__ rel_w,
                                               const float* __restrict__ rel_b,
                                               const float* __restrict__ root_w,
                                               float* __restrict__ Wc,
                                               float* __restrict__ bc) {
    int idx = blockIdx.x * 256 + threadIdx.x;
    if (idx < 256 * T_LEN) {
        int j = idx / T_LEN, i = idx % T_LEN;
        const float* pw = (j < DHID) ? (rel_w + (size_t)j * DLAT)
                                     : (root_w + (size_t)(j - DHID) * DLAT);
        int t0 = i - 12 > 0 ? i - 12 : 0;
        int t1 = i + 12 < T_LEN - 1 ? i + 12 : T_LEN - 1;
        float acc = 0.f;
        for (int c = 0; c < DLAT; ++c) {
            float wci = 0.f;
            for (int t = t0; t <= t1; ++t)
                wci += fc1_w[t] * conv_w[c * K_LEN + (i - t + 12)];
            acc += pw[c] * wci;
        }
        Wc[idx] = acc;
    } else if (idx < 256 * T_LEN + 256) {
        int j = idx - 256 * T_LEN;
        const float* pw = (j < DHID) ? (rel_w + (size_t)j * DLAT)
                                     : (root_w + (size_t)(j - DHID) * DLAT);
        float S = 0.f;
        for (int t = 0; t < T_LEN; ++t) S += fc1_w[t];
        float acc = (j < DHID) ? 0.f : rel_b[j - DHID];
        for (int c = 0; c < DLAT; ++c) acc += pw[c] * (conv_b[c] * S + fc1_b[0]);
        bc[j] = acc;
    }
}

// ---------------------------------------------------------------------------
// phaseB (R3-proven path): per-graph adjacency counts via GLOBAL float
// atomics (+1.0 each -> exact small ints, order-independent). Graph id from
// dst>>6 (no assumption about edge ordering). Layout adjF[g][src][dst] so
// phaseCU part 2 can read, for fixed src s, the 8 dst values of a wave as
// two contiguous float4s.
// ---------------------------------------------------------------------------
__global__ void phaseB(const int* __restrict__ ei, float* __restrict__ adjF,
                       int E) {
    int e = blockIdx.x * blockDim.x + threadIdx.x;
    if (e >= E) return;
    int src = ei[e];
    int dst = ei[E + e];
    int g = dst >> 6;
    atomicAdd(&adjF[((size_t)g << 12) + ((unsigned)(src & 63) << 6) + (unsigned)(dst & 63)], 1.0f);
}

// ---------------------------------------------------------------------------
// phaseCU (block = graph, 512 thr = 8 waves, ~75 KB LDS -> 2 blocks/CU):
//  Part 1: wave w computes channels [32w,32w+32) of U = x@Wc^T + bc for all
//          64 nodes (lane = node). Wc/bc via wave-uniform s_load (pattern
//          validated in R2); x via per-lane float4 (L1-resident tile).
//          P channels (j<128) -> Pb LDS [node][130]; R channels -> RB LDS.
//  R-extract: thread (w,lane) pulls its R values (nodes 8w..8w+8, channels
//          lane/lane+64) into registers; RB is then REUSED for the A matrix.
//  A-load: cooperative vector float4 loads of adjF[g] -> RB[0..4096).
//  Part 2: for s in 0..64: v0=Pb[s][lane], v1=Pb[s][64+lane] (wave b32 reads,
//          conflict-free), A[8w..8w+8, s] via two uniform ds_read_b128;
//          16 FMAs. No scalar-memory reads of same-launch data anywhere.
//  Epilogue: out = acc + R_regs; per-wave S/Q partials -> red -> Sg/Qg.
// ---------------------------------------------------------------------------
__global__ __launch_bounds__(512, 4) void phaseCU(const float* __restrict__ x,
                                                  const float* __restrict__ Wc,
                                                  const float* __restrict__ bc,
                                                  const float* __restrict__ adjF,
                                                  float* __restrict__ Sg,
                                                  float* __restrict__ Qg) {
    __shared__ float Pb[64 * 130];   // 33.3 KB: P[node][ch<128]
    __shared__ float RB[64 * 130];   // 33.3 KB: R transpose buffer, then A
    __shared__ float red[2 * 8 * 130];

    int tid = threadIdx.x;
    int lane = tid & 63;
    int w = __builtin_amdgcn_readfirstlane(tid >> 6);  // 0..7 uniform
    int g = blockIdx.x;

    // ---- Part 1: U = x @ Wc^T + bc ----
    const float4* __restrict__ xp =
        (const float4*)(x + ((size_t)g * 64 + lane) * T_LEN);
    const float* __restrict__ Wb = Wc + (size_t)w * 32 * T_LEN;  // uniform

    for (int cg = 0; cg < 4; ++cg) {
        float acc[8];
#pragma unroll
        for (int c = 0; c < 8; ++c) acc[c] = bc[w * 32 + cg * 8 + c];
#pragma unroll
        for (int tq = 0; tq < T_LEN / 4; ++tq) {
            float4 xv = xp[tq];
#pragma unroll
            for (int c = 0; c < 8; ++c) {
                const float* wr = Wb + (cg * 8 + c) * T_LEN + tq * 4;  // s_load
                acc[c] += xv.x * wr[0] + xv.y * wr[1] + xv.z * wr[2] + xv.w * wr[3];
            }
        }
        int j0 = w * 32 + cg * 8;
        float* dst = (w < 4) ? (&Pb[lane * 130 + j0])
                             : (&RB[lane * 130 + (j0 - DHID)]);
        float4 o0 = {acc[0], acc[1], acc[2], acc[3]};
        float4 o1 = {acc[4], acc[5], acc[6], acc[7]};
        *(float4*)(dst) = o0;
        *(float4*)(dst + 4) = o1;
    }
    __syncthreads();

    // ---- R-extract: this thread's root-path values into registers ----
    float rr0[8], rr1[8];
#pragma unroll
    for (int n8 = 0; n8 < 8; ++n8) {
        rr0[n8] = RB[(8 * w + n8) * 130 + lane];
        rr1[n8] = RB[(8 * w + n8) * 130 + 64 + lane];
    }
    __syncthreads();

    // ---- A-load: RB reused as A[src][dst] (4096 floats) ----
    {
        const float4* __restrict__ Af4 = (const float4*)(adjF + ((size_t)g << 12));
        for (int i4 = tid; i4 < 1024; i4 += 512)
            *(float4*)&RB[4 * i4] = Af4[i4];
    }
    __syncthreads();

    // ---- Part 2: agg[n, j] = sum_s A[n,s] * P[s,j] ----
    float acc2[16];
#pragma unroll
    for (int i = 0; i < 16; ++i) acc2[i] = 0.f;

    for (int s = 0; s < 64; ++s) {
        float v0 = Pb[s * 130 + lane];
        float v1 = Pb[s * 130 + 64 + lane];
        float4 a0 = *(const float4*)&RB[s * 64 + 8 * w];      // uniform bcast
        float4 a1 = *(const float4*)&RB[s * 64 + 8 * w + 4];  // uniform bcast
        acc2[0]  += a0.x * v0; acc2[1]  += a0.x * v1;
        acc2[2]  += a0.y * v0; acc2[3]  += a0.y * v1;
        acc2[4]  += a0.z * v0; acc2[5]  += a0.z * v1;
        acc2[6]  += a0.w * v0; acc2[7]  += a0.w * v1;
        acc2[8]  += a1.x * v0; acc2[9]  += a1.x * v1;
        acc2[10] += a1.y * v0; acc2[11] += a1.y * v1;
        acc2[12] += a1.z * v0; acc2[13] += a1.z * v1;
        acc2[14] += a1.w * v0; acc2[15] += a1.w * v1;
    }

    // ---- Epilogue: add R, square, reduce over n ----
    float sj0 = 0.f, qj0 = 0.f, sj1 = 0.f, qj1 = 0.f;
#pragma unroll
    for (int n8 = 0; n8 < 8; ++n8) {
        float o0 = acc2[2 * n8] + rr0[n8];
        float o1 = acc2[2 * n8 + 1] + rr1[n8];
        sj0 += o0; qj0 += o0 * o0;
        sj1 += o1; qj1 += o1 * o1;
    }
    float* redS = red;
    float* redQ = red + 8 * 130;
    redS[w * 130 + lane] = sj0;
    redS[w * 130 + 64 + lane] = sj1;
    redQ[w * 130 + lane] = qj0;
    redQ[w * 130 + 64 + lane] = qj1;
    __syncthreads();

    if (tid < DHID) {
        float S = 0.f, Q = 0.f;
#pragma unroll
        for (int w8 = 0; w8 < 8; ++w8) {
            S += redS[w8 * 130 + tid];
            Q += redQ[w8 * 130 + tid];
        }
        Sg[(size_t)g * DHID + tid] = S;
        Qg[(size_t)g * DHID + tid] = Q;
    }
}

// ---------------------------------------------------------------------------
// phaseD: BN stats per channel -> scale a[j], shift b[j]
// ---------------------------------------------------------------------------
__global__ __launch_bounds__(64) void phaseD(const float* __restrict__ Sg,
                                             const float* __restrict__ Qg,
                                             const float* __restrict__ gamma,
                                             const float* __restrict__ beta,
                                             float* __restrict__ ab,
                                             int G, int N) {
    int j = blockIdx.x;
    int t = threadIdx.x;
    float s = 0.f, q = 0.f;
    for (int g = t; g < G; g += 64) {
        s += Sg[g * DHID + j];
        q += Qg[g * DHID + j];
    }
#pragma unroll
    for (int off = 32; off; off >>= 1) {
        s += __shfl_xor(s, off);
        q += __shfl_xor(q, off);
    }
    if (t == 0) {
        float inv_n = 1.f / (float)N;
        float mean = s * inv_n;
        float var = q * inv_n - mean * mean;
        float a = rsqrtf(var + 1e-5f) * gamma[j];
        float b = beta[j] - mean * a;
        ab[j] = a;
        ab[DHID + j] = b;
    }
}

// ---------------------------------------------------------------------------
// phaseE: pooled = (a^2 Q + 2ab S)/64 + b^2 ; log(clamp) ; fc2 ; sigmoid
// ---------------------------------------------------------------------------
__global__ __launch_bounds__(128) void phaseE(const float* __restrict__ Sg,
                                              const float* __restrict__ Qg,
                                              const float* __restrict__ ab,
                                              const float* __restrict__ fc2_w,
                                              const float* __restrict__ fc2_b,
                                              float* __restrict__ y) {
    int g = blockIdx.x;
    int j = threadIdx.x;
    __shared__ float ps[DHID];
    float a = ab[j], b = ab[DHID + j];
    float S = Sg[g * DHID + j], Q = Qg[g * DHID + j];
    float pooled = (a * a * Q + 2.f * a * b * S) * (1.f / 64.f) + b * b;
    pooled = fmaxf(pooled, 1e-6f);
    ps[j] = logf(pooled);
    __syncthreads();
    if (j < 3) {
        float acc = fc2_b[j];
        for (int c = 0; c < DHID; ++c) acc += ps[c] * fc2_w[j * DHID + c];
        y[g * 3 + j] = 1.f / (1.f + expf(-acc));
    }
}

// ---------------------------------------------------------------------------
extern "C" void kernel_launch(void* const* d_in, const int* in_sizes, int n_in,
                              void* d_out, int out_size, void* d_ws, size_t ws_size,
                              hipStream_t stream) {
    const float* x      = (const float*)d_in[0];
    const int*   ei     = (const int*)d_in[1];
    const float* conv_w = (const float*)d_in[3];
    const float* conv_b = (const float*)d_in[4];
    const float* fc1_w  = (const float*)d_in[5];
    const float* fc1_b  = (const float*)d_in[6];
    const float* rel_w  = (const float*)d_in[7];
    const float* rel_b  = (const float*)d_in[8];
    const float* root_w = (const float*)d_in[9];
    const float* gamma  = (const float*)d_in[10];
    const float* beta   = (const float*)d_in[11];
    const float* fc2_w  = (const float*)d_in[12];
    const float* fc2_b  = (const float*)d_in[13];
    float* y = (float*)d_out;

    int N = in_sizes[2];       // 32768
    int E = in_sizes[1] / 2;   // 1048576
    int G = N / 64;            // 512

    float* ws   = (float*)d_ws;
    float* adjF = ws;                       // G*4096 (8 MB)
    float* Sg   = adjF + (size_t)G * 4096;  // G*128
    float* Qg   = Sg + (size_t)G * DHID;    // G*128
    float* ab   = Qg + (size_t)G * DHID;    // 256
    float* Wc   = ab + 2 * DHID;            // 256*100
    float* bc   = Wc + 256 * T_LEN;         // 256

    hipMemsetAsync(adjF, 0, (size_t)G * 4096 * 4, stream);
    buildWc<<<101, 256, 0, stream>>>(conv_w, conv_b, fc1_w, fc1_b,
                                     rel_w, rel_b, root_w, Wc, bc);
    phaseB<<<(E + 255) / 256, 256, 0, stream>>>(ei, adjF, E);
    phaseCU<<<G, 512, 0, stream>>>(x, Wc, bc, adjF, Sg, Qg);
    phaseD<<<DHID, 64, 0, stream>>>(Sg, Qg, gamma, beta, ab, G, N);
    phaseE<<<G, DHID, 0, stream>>>(Sg, Qg, ab, fc2_w, fc2_b, y);
}

// Round 6
// 370.811 us; speedup vs baseline: 1.2537x; 1.2537x over previous
//
#include <hip/hip_runtime.h>
#include <math.h>

#define T_LEN 100
#define K_LEN 25
#define DLAT 64
#define DHID 128

// ---------------------------------------------------------------------------
// buildWc: fold Conv1d+fc1+{rel,root} projections into one 256x100 matrix:
//   U[n,j] = sum_i x[n,i]*Wc[j,i] + bc[j]
//   j <  128: P[n,j] (rel path, pre-aggregation)   Wc[j,:] = rel_w[j,:] @ W
//   j >= 128: R[n,j'] (root path + rel_b)          Wc[j,:] = root_w[j',:] @ W
//   W[c,i] = sum_t fc1_w[t] * conv_w[c, i-t+12]
// ---------------------------------------------------------------------------
__global__ __launch_bounds__(256) void buildWc(const float* __restrict__ conv_w,
                                               const float* __restrict__ conv_b,
                                               const float* __restrict__ fc1_w,
                                               const float* __restrict__ fc1_b,
                                               const float* __restrict__ rel_w,
                                               const float* __restrict__ rel_b,
                                               const float* __restrict__ root_w,
                                               float* __restrict__ Wc,
                                               float* __restrict__ bc) {
    int idx = blockIdx.x * 256 + threadIdx.x;
    if (idx < 256 * T_LEN) {
        int j = idx / T_LEN, i = idx % T_LEN;
        const float* pw = (j < DHID) ? (rel_w + (size_t)j * DLAT)
                                     : (root_w + (size_t)(j - DHID) * DLAT);
        int t0 = i - 12 > 0 ? i - 12 : 0;
        int t1 = i + 12 < T_LEN - 1 ? i + 12 : T_LEN - 1;
        float acc = 0.f;
        for (int c = 0; c < DLAT; ++c) {
            float wci = 0.f;
            for (int t = t0; t <= t1; ++t)
                wci += fc1_w[t] * conv_w[c * K_LEN + (i - t + 12)];
            acc += pw[c] * wci;
        }
        Wc[idx] = acc;
    } else if (idx < 256 * T_LEN + 256) {
        int j = idx - 256 * T_LEN;
        const float* pw = (j < DHID) ? (rel_w + (size_t)j * DLAT)
                                     : (root_w + (size_t)(j - DHID) * DLAT);
        float S = 0.f;
        for (int t = 0; t < T_LEN; ++t) S += fc1_w[t];
        float acc = (j < DHID) ? 0.f : rel_b[j - DHID];
        for (int c = 0; c < DLAT; ++c) acc += pw[c] * (conv_b[c] * S + fc1_b[0]);
        bc[j] = acc;
    }
}

// ---------------------------------------------------------------------------
// phaseB: per-graph adjacency counts via GLOBAL float atomics (+1.0 each ->
// exact small ints, order-independent). Graph id from dst>>6. Layout
// adjF[g][src][dst] so phaseCU part 2 reads A rows as contiguous float4s.
// ---------------------------------------------------------------------------
__global__ void phaseB(const int* __restrict__ ei, float* __restrict__ adjF,
                       int E) {
    int e = blockIdx.x * blockDim.x + threadIdx.x;
    if (e >= E) return;
    int src = ei[e];
    int dst = ei[E + e];
    int g = dst >> 6;
    atomicAdd(&adjF[((size_t)g << 12) + ((unsigned)(src & 63) << 6) + (unsigned)(dst & 63)], 1.0f);
}

// ---------------------------------------------------------------------------
// phaseCU (block = graph, 512 thr = 8 waves, ~75 KB LDS -> 2 blocks/CU):
//  Part 1: wave w computes channels [32w,32w+32) of U = x@Wc^T + bc for all
//          64 nodes (lane = node), in groups of 8 channels. cg loop is
//          UNROLL 1: prevents cross-iteration CSE of the x float4 loads
//          (which in R5 created a ~140-VGPR live set -> spill storm; x
//          re-reads hit L1). Wc/bc via wave-uniform s_load.
//  R-extract: root-path values to registers; RB reused for A.
//  A-load: cooperative float4 loads of adjF[g] -> RB.
//  Part 2: per s: v0/v1 lane reads of Pb (conflict-free), A[8w..8w+8, s]
//          via two uniform ds_read_b128 broadcasts; 16 FMAs.
//  Epilogue: out = acc + R_regs; per-wave S/Q partials -> red -> Sg/Qg.
//  launch_bounds(512,2): VGPR budget 256 (no forced spill); occupancy is
//  LDS-limited to 2 blocks/CU regardless.
// ---------------------------------------------------------------------------
__global__ __launch_bounds__(512, 2) void phaseCU(const float* __restrict__ x,
                                                  const float* __restrict__ Wc,
                                                  const float* __restrict__ bc,
                                                  const float* __restrict__ adjF,
                                                  float* __restrict__ Sg,
                                                  float* __restrict__ Qg) {
    __shared__ float Pb[64 * 130];   // 33.3 KB: P[node][ch<128]
    __shared__ float RB[64 * 130];   // 33.3 KB: R transpose buffer, then A
    __shared__ float red[2 * 8 * 130];

    int tid = threadIdx.x;
    int lane = tid & 63;
    int w = __builtin_amdgcn_readfirstlane(tid >> 6);  // 0..7 uniform
    int g = blockIdx.x;

    // ---- Part 1: U = x @ Wc^T + bc ----
    const float4* __restrict__ xp =
        (const float4*)(x + ((size_t)g * 64 + lane) * T_LEN);
    const float* __restrict__ Wb = Wc + (size_t)w * 32 * T_LEN;  // uniform

#pragma unroll 1
    for (int cg = 0; cg < 4; ++cg) {
        float acc[8];
#pragma unroll
        for (int c = 0; c < 8; ++c) acc[c] = bc[w * 32 + cg * 8 + c];
#pragma unroll
        for (int tq = 0; tq < T_LEN / 4; ++tq) {
            float4 xv = xp[tq];
#pragma unroll
            for (int c = 0; c < 8; ++c) {
                const float* wr = Wb + (cg * 8 + c) * T_LEN + tq * 4;  // s_load
                acc[c] += xv.x * wr[0] + xv.y * wr[1] + xv.z * wr[2] + xv.w * wr[3];
            }
        }
        int j0 = w * 32 + cg * 8;
        float* dst = (w < 4) ? (&Pb[lane * 130 + j0])
                             : (&RB[lane * 130 + (j0 - DHID)]);
        float4 o0 = {acc[0], acc[1], acc[2], acc[3]};
        float4 o1 = {acc[4], acc[5], acc[6], acc[7]};
        *(float4*)(dst) = o0;
        *(float4*)(dst + 4) = o1;
    }
    __syncthreads();

    // ---- R-extract: this thread's root-path values into registers ----
    float rr0[8], rr1[8];
#pragma unroll
    for (int n8 = 0; n8 < 8; ++n8) {
        rr0[n8] = RB[(8 * w + n8) * 130 + lane];
        rr1[n8] = RB[(8 * w + n8) * 130 + 64 + lane];
    }
    __syncthreads();

    // ---- A-load: RB reused as A[src][dst] (4096 floats) ----
    {
        const float4* __restrict__ Af4 = (const float4*)(adjF + ((size_t)g << 12));
        for (int i4 = tid; i4 < 1024; i4 += 512)
            *(float4*)&RB[4 * i4] = Af4[i4];
    }
    __syncthreads();

    // ---- Part 2: agg[n, j] = sum_s A[n,s] * P[s,j] ----
    float acc2[16];
#pragma unroll
    for (int i = 0; i < 16; ++i) acc2[i] = 0.f;

    for (int s = 0; s < 64; ++s) {
        float v0 = Pb[s * 130 + lane];
        float v1 = Pb[s * 130 + 64 + lane];
        float4 a0 = *(const float4*)&RB[s * 64 + 8 * w];      // uniform bcast
        float4 a1 = *(const float4*)&RB[s * 64 + 8 * w + 4];  // uniform bcast
        acc2[0]  += a0.x * v0; acc2[1]  += a0.x * v1;
        acc2[2]  += a0.y * v0; acc2[3]  += a0.y * v1;
        acc2[4]  += a0.z * v0; acc2[5]  += a0.z * v1;
        acc2[6]  += a0.w * v0; acc2[7]  += a0.w * v1;
        acc2[8]  += a1.x * v0; acc2[9]  += a1.x * v1;
        acc2[10] += a1.y * v0; acc2[11] += a1.y * v1;
        acc2[12] += a1.z * v0; acc2[13] += a1.z * v1;
        acc2[14] += a1.w * v0; acc2[15] += a1.w * v1;
    }

    // ---- Epilogue: add R, square, reduce over n ----
    float sj0 = 0.f, qj0 = 0.f, sj1 = 0.f, qj1 = 0.f;
#pragma unroll
    for (int n8 = 0; n8 < 8; ++n8) {
        float o0 = acc2[2 * n8] + rr0[n8];
        float o1 = acc2[2 * n8 + 1] + rr1[n8];
        sj0 += o0; qj0 += o0 * o0;
        sj1 += o1; qj1 += o1 * o1;
    }
    float* redS = red;
    float* redQ = red + 8 * 130;
    redS[w * 130 + lane] = sj0;
    redS[w * 130 + 64 + lane] = sj1;
    redQ[w * 130 + lane] = qj0;
    redQ[w * 130 + 64 + lane] = qj1;
    __syncthreads();

    if (tid < DHID) {
        float S = 0.f, Q = 0.f;
#pragma unroll
        for (int w8 = 0; w8 < 8; ++w8) {
            S += redS[w8 * 130 + tid];
            Q += redQ[w8 * 130 + tid];
        }
        Sg[(size_t)g * DHID + tid] = S;
        Qg[(size_t)g * DHID + tid] = Q;
    }
}

// ---------------------------------------------------------------------------
// phaseD: BN stats per channel -> scale a[j], shift b[j]
// ---------------------------------------------------------------------------
__global__ __launch_bounds__(64) void phaseD(const float* __restrict__ Sg,
                                             const float* __restrict__ Qg,
                                             const float* __restrict__ gamma,
                                             const float* __restrict__ beta,
                                             float* __restrict__ ab,
                                             int G, int N) {
    int j = blockIdx.x;
    int t = threadIdx.x;
    float s = 0.f, q = 0.f;
    for (int g = t; g < G; g += 64) {
        s += Sg[g * DHID + j];
        q += Qg[g * DHID + j];
    }
#pragma unroll
    for (int off = 32; off; off >>= 1) {
        s += __shfl_xor(s, off);
        q += __shfl_xor(q, off);
    }
    if (t == 0) {
        float inv_n = 1.f / (float)N;
        float mean = s * inv_n;
        float var = q * inv_n - mean * mean;
        float a = rsqrtf(var + 1e-5f) * gamma[j];
        float b = beta[j] - mean * a;
        ab[j] = a;
        ab[DHID + j] = b;
    }
}

// ---------------------------------------------------------------------------
// phaseE: pooled = (a^2 Q + 2ab S)/64 + b^2 ; log(clamp) ; fc2 ; sigmoid
// ---------------------------------------------------------------------------
__global__ __launch_bounds__(128) void phaseE(const float* __restrict__ Sg,
                                              const float* __restrict__ Qg,
                                              const float* __restrict__ ab,
                                              const float* __restrict__ fc2_w,
                                              const float* __restrict__ fc2_b,
                                              float* __restrict__ y) {
    int g = blockIdx.x;
    int j = threadIdx.x;
    __shared__ float ps[DHID];
    float a = ab[j], b = ab[DHID + j];
    float S = Sg[g * DHID + j], Q = Qg[g * DHID + j];
    float pooled = (a * a * Q + 2.f * a * b * S) * (1.f / 64.f) + b * b;
    pooled = fmaxf(pooled, 1e-6f);
    ps[j] = logf(pooled);
    __syncthreads();
    if (j < 3) {
        float acc = fc2_b[j];
        for (int c = 0; c < DHID; ++c) acc += ps[c] * fc2_w[j * DHID + c];
        y[g * 3 + j] = 1.f / (1.f + expf(-acc));
    }
}

// ---------------------------------------------------------------------------
extern "C" void kernel_launch(void* const* d_in, const int* in_sizes, int n_in,
                              void* d_out, int out_size, void* d_ws, size_t ws_size,
                              hipStream_t stream) {
    const float* x      = (const float*)d_in[0];
    const int*   ei     = (const int*)d_in[1];
    const float* conv_w = (const float*)d_in[3];
    const float* conv_b = (const float*)d_in[4];
    const float* fc1_w  = (const float*)d_in[5];
    const float* fc1_b  = (const float*)d_in[6];
    const float* rel_w  = (const float*)d_in[7];
    const float* rel_b  = (const float*)d_in[8];
    const float* root_w = (const float*)d_in[9];
    const float* gamma  = (const float*)d_in[10];
    const float* beta   = (const float*)d_in[11];
    const float* fc2_w  = (const float*)d_in[12];
    const float* fc2_b  = (const float*)d_in[13];
    float* y = (float*)d_out;

    int N = in_sizes[2];       // 32768
    int E = in_sizes[1] / 2;   // 1048576
    int G = N / 64;            // 512

    float* ws   = (float*)d_ws;
    float* adjF = ws;                       // G*4096 (8 MB)
    float* Sg   = adjF + (size_t)G * 4096;  // G*128
    float* Qg   = Sg + (size_t)G * DHID;    // G*128
    float* ab   = Qg + (size_t)G * DHID;    // 256
    float* Wc   = ab + 2 * DHID;            // 256*100
    float* bc   = Wc + 256 * T_LEN;         // 256

    hipMemsetAsync(adjF, 0, (size_t)G * 4096 * 4, stream);
    buildWc<<<101, 256, 0, stream>>>(conv_w, conv_b, fc1_w, fc1_b,
                                     rel_w, rel_b, root_w, Wc, bc);
    phaseB<<<(E + 255) / 256, 256, 0, stream>>>(ei, adjF, E);
    phaseCU<<<G, 512, 0, stream>>>(x, Wc, bc, adjF, Sg, Qg);
    phaseD<<<DHID, 64, 0, stream>>>(Sg, Qg, gamma, beta, ab, G, N);
    phaseE<<<G, DHID, 0, stream>>>(Sg, Qg, ab, fc2_w, fc2_b, y);
}

// Round 7
// 258.868 us; speedup vs baseline: 1.7959x; 1.4324x over previous
//
#include <hip/hip_runtime.h>
#include <math.h>

#define T_LEN 100
#define K_LEN 25
#define DLAT 64
#define DHID 128

// ---------------------------------------------------------------------------
// buildW: stage 1 of the weight fold.
//   idx <  6400 : W[c,i] = sum_t fc1_w[t] * conv_w[c, i-t+12]   (<=25 MAC)
//   idx >= 6400 : bc[j]  = sum_c pw[j,c] * (conv_b[c]*S + fc1_b) (+rel_b)
// ---------------------------------------------------------------------------
__global__ __launch_bounds__(256) void buildW(const float* __restrict__ conv_w,
                                              const float* __restrict__ conv_b,
                                              const float* __restrict__ fc1_w,
                                              const float* __restrict__ fc1_b,
                                              const float* __restrict__ rel_w,
                                              const float* __restrict__ rel_b,
                                              const float* __restrict__ root_w,
                                              float* __restrict__ W,
                                              float* __restrict__ bc) {
    int idx = blockIdx.x * 256 + threadIdx.x;
    if (idx < DLAT * T_LEN) {
        int c = idx / T_LEN, i = idx % T_LEN;
        int t0 = i - 12 > 0 ? i - 12 : 0;
        int t1 = i + 12 < T_LEN - 1 ? i + 12 : T_LEN - 1;
        float acc = 0.f;
        for (int t = t0; t <= t1; ++t)
            acc += fc1_w[t] * conv_w[c * K_LEN + (i - t + 12)];
        W[idx] = acc;
    } else if (idx < DLAT * T_LEN + 256) {
        int j = idx - DLAT * T_LEN;
        const float* pw = (j < DHID) ? (rel_w + (size_t)j * DLAT)
                                     : (root_w + (size_t)(j - DHID) * DLAT);
        float S = 0.f;
        for (int t = 0; t < T_LEN; ++t) S += fc1_w[t];
        float acc = (j < DHID) ? 0.f : rel_b[j - DHID];
        float fb = fc1_b[0];
        for (int c = 0; c < DLAT; ++c) acc += pw[c] * (conv_b[c] * S + fb);
        bc[j] = acc;
    }
}

// ---------------------------------------------------------------------------
// buildWc2: stage 2 — Wc[j,i] = sum_c pw[j,c] * W[c,i].
// Block = one j (256 blocks, 128 thr); lane = i -> coalesced L2-resident W
// reads; pw[j,c] wave-uniform (blockIdx) -> scalar loads. Unroll 8 keeps 8
// independent loads in flight. 64 MAC/thread vs R6's 1600.
// ---------------------------------------------------------------------------
__global__ __launch_bounds__(128) void buildWc2(const float* __restrict__ W,
                                                const float* __restrict__ rel_w,
                                                const float* __restrict__ root_w,
                                                float* __restrict__ Wc) {
    int j = blockIdx.x;
    int i = threadIdx.x;
    if (i >= T_LEN) return;
    const float* __restrict__ pw = (j < DHID) ? (rel_w + (size_t)j * DLAT)
                                              : (root_w + (size_t)(j - DHID) * DLAT);
    float acc = 0.f;
#pragma unroll
    for (int c0 = 0; c0 < DLAT; c0 += 8) {
#pragma unroll
        for (int c = 0; c < 8; ++c)
            acc += pw[c0 + c] * W[(c0 + c) * T_LEN + i];
    }
    Wc[(size_t)j * T_LEN + i] = acc;
}

// ---------------------------------------------------------------------------
// phaseB: per-graph adjacency counts via GLOBAL float atomics (+1.0 each ->
// exact small ints, order-independent). Graph id from dst>>6. Layout
// adjF[g][src][dst] so phaseCU part 2 reads A rows as contiguous float4s.
// ---------------------------------------------------------------------------
__global__ void phaseB(const int* __restrict__ ei, float* __restrict__ adjF,
                       int E) {
    int e = blockIdx.x * blockDim.x + threadIdx.x;
    if (e >= E) return;
    int src = ei[e];
    int dst = ei[E + e];
    int g = dst >> 6;
    atomicAdd(&adjF[((size_t)g << 12) + ((unsigned)(src & 63) << 6) + (unsigned)(dst & 63)], 1.0f);
}

// ---------------------------------------------------------------------------
// phaseCU (block = graph, 512 thr = 8 waves, ~75 KB LDS -> 2 blocks/CU):
//  Part 1: wave w computes channels [32w,32w+32) of U = x@Wc^T + bc for all
//          64 nodes (lane = node), in groups of 8 channels. cg loop is
//          UNROLL 1: prevents cross-iteration CSE of the x float4 loads
//          (R5: ~140-VGPR live set -> spill storm; x re-reads hit L1/L2).
//  R-extract: root-path values to registers; RB reused for A.
//  A-load: cooperative float4 loads of adjF[g] -> RB.
//  Part 2: per s: v0/v1 lane reads of Pb (conflict-free), A[8w..8w+8, s]
//          via two uniform ds_read_b128 broadcasts; 16 FMAs.
//  Epilogue: out = acc + R_regs; per-wave S/Q partials -> red -> Sg/Qg.
// ---------------------------------------------------------------------------
__global__ __launch_bounds__(512, 2) void phaseCU(const float* __restrict__ x,
                                                  const float* __restrict__ Wc,
                                                  const float* __restrict__ bc,
                                                  const float* __restrict__ adjF,
                                                  float* __restrict__ Sg,
                                                  float* __restrict__ Qg) {
    __shared__ float Pb[64 * 130];   // 33.3 KB: P[node][ch<128]
    __shared__ float RB[64 * 130];   // 33.3 KB: R transpose buffer, then A
    __shared__ float red[2 * 8 * 130];

    int tid = threadIdx.x;
    int lane = tid & 63;
    int w = __builtin_amdgcn_readfirstlane(tid >> 6);  // 0..7 uniform
    int g = blockIdx.x;

    // ---- Part 1: U = x @ Wc^T + bc ----
    const float4* __restrict__ xp =
        (const float4*)(x + ((size_t)g * 64 + lane) * T_LEN);
    const float* __restrict__ Wb = Wc + (size_t)w * 32 * T_LEN;  // uniform

#pragma unroll 1
    for (int cg = 0; cg < 4; ++cg) {
        float acc[8];
#pragma unroll
        for (int c = 0; c < 8; ++c) acc[c] = bc[w * 32 + cg * 8 + c];
#pragma unroll
        for (int tq = 0; tq < T_LEN / 4; ++tq) {
            float4 xv = xp[tq];
#pragma unroll
            for (int c = 0; c < 8; ++c) {
                const float* wr = Wb + (cg * 8 + c) * T_LEN + tq * 4;  // s_load
                acc[c] += xv.x * wr[0] + xv.y * wr[1] + xv.z * wr[2] + xv.w * wr[3];
            }
        }
        int j0 = w * 32 + cg * 8;
        float* dst = (w < 4) ? (&Pb[lane * 130 + j0])
                             : (&RB[lane * 130 + (j0 - DHID)]);
        float4 o0 = {acc[0], acc[1], acc[2], acc[3]};
        float4 o1 = {acc[4], acc[5], acc[6], acc[7]};
        *(float4*)(dst) = o0;
        *(float4*)(dst + 4) = o1;
    }
    __syncthreads();

    // ---- R-extract: this thread's root-path values into registers ----
    float rr0[8], rr1[8];
#pragma unroll
    for (int n8 = 0; n8 < 8; ++n8) {
        rr0[n8] = RB[(8 * w + n8) * 130 + lane];
        rr1[n8] = RB[(8 * w + n8) * 130 + 64 + lane];
    }
    __syncthreads();

    // ---- A-load: RB reused as A[src][dst] (4096 floats) ----
    {
        const float4* __restrict__ Af4 = (const float4*)(adjF + ((size_t)g << 12));
        for (int i4 = tid; i4 < 1024; i4 += 512)
            *(float4*)&RB[4 * i4] = Af4[i4];
    }
    __syncthreads();

    // ---- Part 2: agg[n, j] = sum_s A[n,s] * P[s,j] ----
    float acc2[16];
#pragma unroll
    for (int i = 0; i < 16; ++i) acc2[i] = 0.f;

    for (int s = 0; s < 64; ++s) {
        float v0 = Pb[s * 130 + lane];
        float v1 = Pb[s * 130 + 64 + lane];
        float4 a0 = *(const float4*)&RB[s * 64 + 8 * w];      // uniform bcast
        float4 a1 = *(const float4*)&RB[s * 64 + 8 * w + 4];  // uniform bcast
        acc2[0]  += a0.x * v0; acc2[1]  += a0.x * v1;
        acc2[2]  += a0.y * v0; acc2[3]  += a0.y * v1;
        acc2[4]  += a0.z * v0; acc2[5]  += a0.z * v1;
        acc2[6]  += a0.w * v0; acc2[7]  += a0.w * v1;
        acc2[8]  += a1.x * v0; acc2[9]  += a1.x * v1;
        acc2[10] += a1.y * v0; acc2[11] += a1.y * v1;
        acc2[12] += a1.z * v0; acc2[13] += a1.z * v1;
        acc2[14] += a1.w * v0; acc2[15] += a1.w * v1;
    }

    // ---- Epilogue: add R, square, reduce over n ----
    float sj0 = 0.f, qj0 = 0.f, sj1 = 0.f, qj1 = 0.f;
#pragma unroll
    for (int n8 = 0; n8 < 8; ++n8) {
        float o0 = acc2[2 * n8] + rr0[n8];
        float o1 = acc2[2 * n8 + 1] + rr1[n8];
        sj0 += o0; qj0 += o0 * o0;
        sj1 += o1; qj1 += o1 * o1;
    }
    float* redS = red;
    float* redQ = red + 8 * 130;
    redS[w * 130 + lane] = sj0;
    redS[w * 130 + 64 + lane] = sj1;
    redQ[w * 130 + lane] = qj0;
    redQ[w * 130 + 64 + lane] = qj1;
    __syncthreads();

    if (tid < DHID) {
        float S = 0.f, Q = 0.f;
#pragma unroll
        for (int w8 = 0; w8 < 8; ++w8) {
            S += redS[w8 * 130 + tid];
            Q += redQ[w8 * 130 + tid];
        }
        Sg[(size_t)g * DHID + tid] = S;
        Qg[(size_t)g * DHID + tid] = Q;
    }
}

// ---------------------------------------------------------------------------
// phaseD: BN stats per channel -> scale a[j], shift b[j]
// ---------------------------------------------------------------------------
__global__ __launch_bounds__(64) void phaseD(const float* __restrict__ Sg,
                                             const float* __restrict__ Qg,
                                             const float* __restrict__ gamma,
                                             const float* __restrict__ beta,
                                             float* __restrict__ ab,
                                             int G, int N) {
    int j = blockIdx.x;
    int t = threadIdx.x;
    float s = 0.f, q = 0.f;
    for (int g = t; g < G; g += 64) {
        s += Sg[g * DHID + j];
        q += Qg[g * DHID + j];
    }
#pragma unroll
    for (int off = 32; off; off >>= 1) {
        s += __shfl_xor(s, off);
        q += __shfl_xor(q, off);
    }
    if (t == 0) {
        float inv_n = 1.f / (float)N;
        float mean = s * inv_n;
        float var = q * inv_n - mean * mean;
        float a = rsqrtf(var + 1e-5f) * gamma[j];
        float b = beta[j] - mean * a;
        ab[j] = a;
        ab[DHID + j] = b;
    }
}

// ---------------------------------------------------------------------------
// phaseE: pooled = (a^2 Q + 2ab S)/64 + b^2 ; log(clamp) ; fc2 ; sigmoid
// ---------------------------------------------------------------------------
__global__ __launch_bounds__(128) void phaseE(const float* __restrict__ Sg,
                                              const float* __restrict__ Qg,
                                              const float* __restrict__ ab,
                                              const float* __restrict__ fc2_w,
                                              const float* __restrict__ fc2_b,
                                              float* __restrict__ y) {
    int g = blockIdx.x;
    int j = threadIdx.x;
    __shared__ float ps[DHID];
    float a = ab[j], b = ab[DHID + j];
    float S = Sg[g * DHID + j], Q = Qg[g * DHID + j];
    float pooled = (a * a * Q + 2.f * a * b * S) * (1.f / 64.f) + b * b;
    pooled = fmaxf(pooled, 1e-6f);
    ps[j] = logf(pooled);
    __syncthreads();
    if (j < 3) {
        float acc = fc2_b[j];
        for (int c = 0; c < DHID; ++c) acc += ps[c] * fc2_w[j * DHID + c];
        y[g * 3 + j] = 1.f / (1.f + expf(-acc));
    }
}

// ---------------------------------------------------------------------------
extern "C" void kernel_launch(void* const* d_in, const int* in_sizes, int n_in,
                              void* d_out, int out_size, void* d_ws, size_t ws_size,
                              hipStream_t stream) {
    const float* x      = (const float*)d_in[0];
    const int*   ei     = (const int*)d_in[1];
    const float* conv_w = (const float*)d_in[3];
    const float* conv_b = (const float*)d_in[4];
    const float* fc1_w  = (const float*)d_in[5];
    const float* fc1_b  = (const float*)d_in[6];
    const float* rel_w  = (const float*)d_in[7];
    const float* rel_b  = (const float*)d_in[8];
    const float* root_w = (const float*)d_in[9];
    const float* gamma  = (const float*)d_in[10];
    const float* beta   = (const float*)d_in[11];
    const float* fc2_w  = (const float*)d_in[12];
    const float* fc2_b  = (const float*)d_in[13];
    float* y = (float*)d_out;

    int N = in_sizes[2];       // 32768
    int E = in_sizes[1] / 2;   // 1048576
    int G = N / 64;            // 512

    float* ws   = (float*)d_ws;
    float* adjF = ws;                       // G*4096 (8 MB)
    float* Sg   = adjF + (size_t)G * 4096;  // G*128
    float* Qg   = Sg + (size_t)G * DHID;    // G*128
    float* ab   = Qg + (size_t)G * DHID;    // 256
    float* Wc   = ab + 2 * DHID;            // 256*100
    float* bc   = Wc + 256 * T_LEN;         // 256
    float* W    = bc + 256;                 // 64*100

    hipMemsetAsync(adjF, 0, (size_t)G * 4096 * 4, stream);
    buildW<<<26, 256, 0, stream>>>(conv_w, conv_b, fc1_w, fc1_b,
                                   rel_w, rel_b, root_w, W, bc);
    buildWc2<<<256, 128, 0, stream>>>(W, rel_w, root_w, Wc);
    phaseB<<<(E + 255) / 256, 256, 0, stream>>>(ei, adjF, E);
    phaseCU<<<G, 512, 0, stream>>>(x, Wc, bc, adjF, Sg, Qg);
    phaseD<<<DHID, 64, 0, stream>>>(Sg, Qg, gamma, beta, ab, G, N);
    phaseE<<<G, DHID, 0, stream>>>(Sg, Qg, ab, fc2_w, fc2_b, y);
}